// Round 9
// baseline (204.417 us; speedup 1.0000x reference)
//
#include <hip/hip_runtime.h>
#include <stdint.h>

#define B 8192
#define D 128
#define MARGIN 0.3f
#define EPS 1e-6f
#define HALFN (1u << 25)   // B*B/2 = 2^25
#define NCHUNK 64          // j-chunks for main kernel
#define JCH (B / NCHUNK)   // 128
#define NPART 2048         // finalize partial-sum blocks

using bf16x8 = __attribute__((ext_vector_type(8))) short;   // 8 bf16 = 4 VGPRs
using f32x16 = __attribute__((ext_vector_type(16))) float;  // MFMA 32x32 acc

// ---- Threefry-2x32 (JAX-compatible: 20 rounds, 5 key injections) ----
__host__ __device__ __forceinline__ void tf2x32(uint32_t k0, uint32_t k1,
                                                uint32_t x0, uint32_t x1,
                                                uint32_t& o0, uint32_t& o1) {
  uint32_t ks2 = k0 ^ k1 ^ 0x1BD11BDAu;
  uint32_t v0 = x0 + k0, v1 = x1 + k1;
#define RND(r) { v0 += v1; v1 = (v1 << (r)) | (v1 >> (32 - (r))); v1 ^= v0; }
  RND(13) RND(15) RND(26) RND(6)
  v0 += k1;  v1 += ks2 + 1u;
  RND(17) RND(29) RND(16) RND(24)
  v0 += ks2; v1 += k0 + 2u;
  RND(13) RND(15) RND(26) RND(6)
  v0 += k0;  v1 += k1 + 3u;
  RND(17) RND(29) RND(16) RND(24)
  v0 += k1;  v1 += ks2 + 4u;
  RND(13) RND(15) RND(26) RND(6)
  v0 += ks2; v1 += k0 + 5u;
#undef RND
  o0 = v0; o1 = v1;
}

// device rounds-only variant: caller pre-adds the key to the counter
// (v0 = x0 + k0, v1 = x1 + k1 hoisted as per-lane constants + j).
__device__ __forceinline__ void tf_rounds(uint32_t k0, uint32_t k1,
                                          uint32_t v0, uint32_t v1,
                                          uint32_t& o0, uint32_t& o1) {
  uint32_t ks2 = k0 ^ k1 ^ 0x1BD11BDAu;
#define RNDL(r) { v0 += v1; v1 = __builtin_rotateleft32(v1, r); v1 ^= v0; }
  RNDL(13) RNDL(15) RNDL(26) RNDL(6)
  v0 += k1;  v1 += ks2 + 1u;
  RNDL(17) RNDL(29) RNDL(16) RNDL(24)
  v0 += ks2; v1 += k0 + 2u;
  RNDL(13) RNDL(15) RNDL(26) RNDL(6)
  v0 += k0;  v1 += k1 + 3u;
  RNDL(17) RNDL(29) RNDL(16) RNDL(24)
  v0 += k1;  v1 += ks2 + 4u;
  RNDL(13) RNDL(15) RNDL(26) RNDL(6)
  v0 += ks2; v1 += k0 + 5u;
#undef RNDL
  o0 = v0; o1 = v1;
}

// gumbel-argmax reduces to integer compare on (bits >> 9) -- strictly monotone.
__device__ __forceinline__ uint32_t gbits(uint32_t k0, uint32_t k1, uint32_t f) {
  bool lo = f < HALFN;
  uint32_t x0 = lo ? f : f - HALFN;
  uint32_t x1 = lo ? f + HALFN : f;
  uint32_t o0, o1;
  tf2x32(k0, k1, x0, x1, o0, o1);
  return (lo ? o0 : o1) >> 9;
}

__device__ __forceinline__ uint16_t f2bf(float f) {   // RNE float->bf16
  uint32_t u = __float_as_uint(f);
  return (uint16_t)((u + 0x7FFFu + ((u >> 16) & 1u)) >> 16);
}
__device__ __forceinline__ float bf2f(uint16_t b) {
  return __uint_as_float((uint32_t)b << 16);
}
__device__ __forceinline__ bf16x8 as_bf(uint4 u) {
  union { uint4 a; bf16x8 b; } x; x.a = u; return x.b;
}

// ---- 1. fused prep + positive mining ----
// All 2048 blocks: pos phase for 4 anchors each (inline norms -> no dependency
// on prep output). Blocks < 512 additionally do the bf16 hi/lo chunk split +
// row-norm sq (consumed only by the LATER main launch).
__global__ __launch_bounds__(256) void pp_kernel(
    const float* __restrict__ emb, const int* __restrict__ labels,
    uint32_t kp0, uint32_t kp1,
    uint32_t* __restrict__ chunk, float* __restrict__ sq,
    int* __restrict__ posx, float* __restrict__ ap2lo, float* __restrict__ ap2hi,
    int* __restrict__ validf,
    uint32_t* __restrict__ semikey, uint32_t* __restrict__ hardkey,
    uint32_t* __restrict__ ticket) {
  __shared__ int s_cnt[4];
  __shared__ int s_list[4][80];
  int wid = threadIdx.x >> 6, lane = threadIdx.x & 63;
  int i = blockIdx.x * 4 + wid;

  if (blockIdx.x == 0 && threadIdx.x == 0) *ticket = 0u;
  if (lane == 0) { semikey[i] = 0u; hardkey[i] = 0xFFFFFFFFu; s_cnt[wid] = 0; }

  // ---- prep phase (chunk layout: [g=row/32][kk=k/16][h][lane=(ksub<<5)|row%32] x16B) ----
  if (blockIdx.x < 512) {
    int tid = blockIdx.x * 256 + threadIdx.x;   // 131072 total
    int row = tid >> 4, oct = tid & 15;
    const float* src = emb + row * D + oct * 8;
    uint32_t hi[4], lo[4];
    float s = 0.0f;
    #pragma unroll
    for (int e = 0; e < 4; e++) {
      float f0 = src[2 * e], f1 = src[2 * e + 1];
      s = fmaf(f0, f0, s); s = fmaf(f1, f1, s);
      uint16_t h0 = f2bf(f0), h1 = f2bf(f1);
      uint16_t l0 = f2bf(__fsub_rn(f0, bf2f(h0)));
      uint16_t l1 = f2bf(__fsub_rn(f1, bf2f(h1)));
      hi[e] = (uint32_t)h0 | ((uint32_t)h1 << 16);
      lo[e] = (uint32_t)l0 | ((uint32_t)l1 << 16);
    }
    s += __shfl_xor(s, 1); s += __shfl_xor(s, 2);
    s += __shfl_xor(s, 4); s += __shfl_xor(s, 8);
    if (oct == 0) sq[row] = s;
    int g = row >> 5, kk = oct >> 1, ln = ((oct & 1) << 5) | (row & 31);
    uint32_t base = ((g * 8 + kk) * 2) * 64 + ln;        // chunk index, h=0
    *(uint4*)&chunk[(size_t)base * 4]        = make_uint4(hi[0], hi[1], hi[2], hi[3]);
    *(uint4*)&chunk[(size_t)(base + 64) * 4] = make_uint4(lo[0], lo[1], lo[2], lo[3]);
  }

  // ---- pos phase: compact same-label list in LDS, then dense tf pass ----
  int lab = labels[i];
  __syncthreads();
  for (int it = 0; it < B / 256; it++) {     // 32 iters of int4
    int j0 = it * 256 + lane * 4;
    int4 lv = *(const int4*)&labels[j0];
    #pragma unroll
    for (int e = 0; e < 4; e++) {
      if ((&lv.x)[e] == lab) {
        int pp = atomicAdd(&s_cnt[wid], 1);
        if (pp < 80) s_list[wid][pp] = j0 + e;
      }
    }
  }
  __syncthreads();
  int cnt = s_cnt[wid];

  // dense tf over ~16 candidates (list order random -> order-independent tie-break)
  uint32_t fbase = (uint32_t)i << 13;
  uint32_t bb = 0; int bi = -1;
  for (int t = lane; t < cnt; t += 64) {
    int j = s_list[wid][t];
    if (j != i) {
      uint32_t bits = gbits(kp0, kp1, fbase | (uint32_t)j);
      if (bi < 0 || bits > bb || (bits == bb && j < bi)) { bb = bits; bi = j; }
    }
  }
  #pragma unroll
  for (int off = 32; off > 0; off >>= 1) {
    uint32_t ob = __shfl_xor(bb, off);
    int oi = __shfl_xor(bi, off);
    if (oi >= 0 && (bi < 0 || ob > bb || (ob == bb && oi < bi))) { bb = ob; bi = oi; }
  }
  int pidx = (cnt >= 2) ? bi : 0;   // no positive -> argmax(-inf)=0

  float a0 = emb[i * D + lane],    a1 = emb[i * D + 64 + lane];
  float p0 = emb[pidx * D + lane], p1 = emb[pidx * D + 64 + lane];
  float dot = fmaf(a1, p1, a0 * p0);
  float sqi = fmaf(a1, a1, a0 * a0);
  float sqp = fmaf(p1, p1, p0 * p0);
  #pragma unroll
  for (int off = 32; off > 0; off >>= 1) {
    dot += __shfl_xor(dot, off);
    sqi += __shfl_xor(sqi, off);
    sqp += __shfl_xor(sqp, off);
  }

  if (lane == 0) {
    float d2 = __fadd_rn(__fsub_rn(sqp, __fmul_rn(2.0f, dot)), sqi);
    float apv = __fsqrt_rn(fmaxf(d2, 0.0f));
    float apm = __fadd_rn(apv, MARGIN);
    ap2lo[i] = __fmul_rn(apv, apv);           // band test in d^2 domain
    ap2hi[i] = __fmul_rn(apm, apm);
    posx[i] = pidx;
    validf[i] = (cnt >= 2 && cnt < B) ? 1 : 0;
  }
}

// ---- 2. main: swapped-operand MFMA + register-local mining, u32 keys ----
// grid (32 anchor-blocks, 64 j-chunks) x 256 thr -> 2048 blocks (8-deep/CU
// queue smooths barrier stalls).
// __launch_bounds__(256,3): the (256,4)=128-reg cap spilled TWICE (R5, R7:
// scratch FETCH 146 MB, VALUBusy 58%); this kernel needs the 170-reg budget.
// Xb = fma(-2, dot, sq[j]+4) > 0 is simultaneously the band-test value
// (vs per-lane pre-shifted thresholds) and bit-monotone hard-min key.
// semi key: (o & 0xFFFFE000)|(8191-j) == (gumbelbits19<<13)|(8191-j),
//           v_max_u32 merge (0 = none).
// hard key: (Xbits & ~8191) | j, v_min_u32 merge (~0 = none).
__global__ __launch_bounds__(256, 3) void main_kernel(
    const uint32_t* __restrict__ chunk, const int* __restrict__ labels,
    const float* __restrict__ sq, const float* __restrict__ ap2lo,
    const float* __restrict__ ap2hi, uint32_t kn0, uint32_t kn1,
    uint32_t* __restrict__ semikey, uint32_t* __restrict__ hardkey) {
  __shared__ uint32_t ldsB[8192];   // 32 KB: [n0][kk][h][lane] 16B chunks (j rows)
  __shared__ float2 s_ji[64];       // .x = sq[j]+4, .y = as_float(label[j])

  const int tid = threadIdx.x;
  const int w = tid >> 6, lane = tid & 63;
  const int p = lane & 31, khalf = lane >> 5;
  const int A0 = blockIdx.x * 128;
  const int jc = blockIdx.y;
  const int ia_lo = A0 + 32 * w + p;
  const int ia_up = ia_lo + 4096;

  // anchor B-frags (hi only): 2 tiles x 8 ksteps = 16 x 16B = 64 VGPRs
  bf16x8 Af[2][8];
  {
    int g_lo = (A0 >> 5) + w;
    #pragma unroll
    for (int m = 0; m < 2; m++) {
      int g = g_lo + (m ? 128 : 0);
      #pragma unroll
      for (int kk = 0; kk < 8; kk++)
        Af[m][kk] = as_bf(*(const uint4*)&chunk[(size_t)(((g * 8 + kk) * 2) * 64 + lane) * 4]);
    }
  }

  const int lab_lo = labels[ia_lo], lab_up = labels[ia_up];
  const float sq_lo = sq[ia_lo], sq_up = sq[ia_up];
  // pre-shifted band thresholds in Xb domain (Xb = d2 - sq_anchor + 4)
  const float Xlo_lo = __fadd_rn(__fsub_rn(ap2lo[ia_lo], sq_lo), 4.0f);
  const float Xhi_lo = __fadd_rn(__fsub_rn(ap2hi[ia_lo], sq_lo), 4.0f);
  const float Xlo_up = __fadd_rn(__fsub_rn(ap2lo[ia_up], sq_up), 4.0f);
  const float Xhi_up = __fadd_rn(__fsub_rn(ap2hi[ia_up], sq_up), 4.0f);
  // hoisted threefry counter bases: v0 = c0 + j, v1 = c1 + j
  const uint32_t c0 = ((uint32_t)ia_lo << 13) + kn0;
  const uint32_t c1 = ((uint32_t)ia_lo << 13) + HALFN + kn1;
  uint32_t sk_lo = 0u, sk_up = 0u;
  uint32_t hk_lo = 0xFFFFFFFFu, hk_up = 0xFFFFFFFFu;

  for (int jt = 0; jt < JCH; jt += 64) {    // 2 j-tiles
    const int jb = jc * JCH + jt;
    __syncthreads();
    {
      const uint32_t* src = chunk + (size_t)(jb >> 5) * 4096;  // 2 groups = 8192 dwords
      #pragma unroll
      for (int q = 0; q < 8; q++) {
        int idx = tid + 256 * q;
        *(uint4*)&ldsB[idx * 4] = *(const uint4*)&src[idx * 4];
      }
      if (tid < 64)
        s_ji[tid] = make_float2(sq[jb + tid] + 4.0f, __int_as_float(labels[jb + tid]));
    }
    __syncthreads();

    #pragma unroll
    for (int n0 = 0; n0 < 2; n0++) {
      f32x16 acc[2];   // [m = anchor tile lo/up] -- reused across n0 (reg pressure)
      acc[0] = (f32x16)(0.0f);
      acc[1] = (f32x16)(0.0f);

      #pragma unroll
      for (int kk = 0; kk < 8; kk++) {
        bf16x8 jh = *(const bf16x8*)&ldsB[(size_t)((n0 * 16 + kk * 2 + 0) * 64 + lane) * 4];
        bf16x8 jl = *(const bf16x8*)&ldsB[(size_t)((n0 * 16 + kk * 2 + 1) * 64 + lane) * 4];
        acc[0] = __builtin_amdgcn_mfma_f32_32x32x16_bf16(jh, Af[0][kk], acc[0], 0, 0, 0);
        acc[0] = __builtin_amdgcn_mfma_f32_32x32x16_bf16(jl, Af[0][kk], acc[0], 0, 0, 0);
        acc[1] = __builtin_amdgcn_mfma_f32_32x32x16_bf16(jh, Af[1][kk], acc[1], 0, 0, 0);
        acc[1] = __builtin_amdgcn_mfma_f32_32x32x16_bf16(jl, Af[1][kk], acc[1], 0, 0, 0);
      }

      // mining epilogue: groups of 4 j's -> 4 independent threefry chains (ILP)
      #pragma unroll
      for (int g = 0; g < 4; g++) {
        uint32_t olo[4], oup[4];
        #pragma unroll
        for (int t = 0; t < 4; t++) {
          int row = t + (g << 3) + (khalf << 2);
          uint32_t jv = (uint32_t)(jb + n0 * 32 + row);
          tf_rounds(kn0, kn1, c0 + jv, c1 + jv, olo[t], oup[t]);  // o0->i, o1->i+4096
        }
        #pragma unroll
        for (int t = 0; t < 4; t++) {
          int r = (g << 2) + t;
          int row = t + (g << 3) + (khalf << 2);
          int jl_ = n0 * 32 + row;
          int j = jb + jl_;
          float2 ji = s_ji[jl_];
          int lj = __float_as_int(ji.y);
          float Xl = fmaf(-2.0f, acc[0][r], ji.x);
          float Xu = fmaf(-2.0f, acc[1][r], ji.x);
          bool nl = (lj != lab_lo), nu = (lj != lab_up);
          uint32_t rj = (uint32_t)(8191 - j);
          uint32_t keyl = (olo[t] & 0xFFFFE000u) | rj;   // == (bits19<<13)|rj
          uint32_t keyu = (oup[t] & 0xFFFFE000u) | rj;
          bool il = nl && (Xl > Xlo_lo) && (Xl < Xhi_lo);
          bool iu = nu && (Xu > Xlo_up) && (Xu < Xhi_up);
          uint32_t csl = il ? keyl : 0u;
          uint32_t csu = iu ? keyu : 0u;
          sk_lo = max(sk_lo, csl);
          sk_up = max(sk_up, csu);
          uint32_t hl = nl ? ((__float_as_uint(Xl) & 0xFFFFE000u) | (uint32_t)j) : 0xFFFFFFFFu;
          uint32_t hu = nu ? ((__float_as_uint(Xu) & 0xFFFFE000u) | (uint32_t)j) : 0xFFFFFFFFu;
          hk_lo = min(hk_lo, hl);
          hk_up = min(hk_up, hu);
        }
      }
    }
  }

  // merge khalf halves (lane ^ 32 holds same anchor pair, other j-rows)
  {
    uint32_t o;
    o = __shfl_xor(sk_lo, 32); sk_lo = max(sk_lo, o);
    o = __shfl_xor(sk_up, 32); sk_up = max(sk_up, o);
    o = __shfl_xor(hk_lo, 32); hk_lo = min(hk_lo, o);
    o = __shfl_xor(hk_up, 32); hk_up = min(hk_up, o);
  }
  if (lane < 32) {
    atomicMax(&semikey[ia_lo], sk_lo);
    atomicMin(&hardkey[ia_lo], hk_lo);
  } else {
    atomicMax(&semikey[ia_up], sk_up);
    atomicMin(&hardkey[ia_up], hk_up);
  }
}

// ---- 3. triplet loss -> per-block partials + last-block final reduction ----
__global__ __launch_bounds__(256) void finalize_kernel(
    const float* __restrict__ emb, const int* __restrict__ posx,
    const int* __restrict__ validf,
    const uint32_t* __restrict__ semikey, const uint32_t* __restrict__ hardkey,
    float* __restrict__ pers, float* __restrict__ cnts,
    uint32_t* __restrict__ ticket, float* __restrict__ out) {
  __shared__ float s_per[4];
  __shared__ float s_cnt[4];
  __shared__ float s_rp[4], s_rc[4];
  __shared__ int s_last;
  int wid = threadIdx.x >> 6, lane = threadIdx.x & 63;
  int i = blockIdx.x * 4 + wid;

  uint32_t sk = semikey[i];
  uint32_t hk = hardkey[i];
  int neg = sk ? (8191 - (int)(sk & 8191u)) : (int)(hk & 8191u);
  if (!sk && hk == 0xFFFFFFFFu) neg = 0;    // no negatives at all (masked by valid)
  int pos = posx[i];

  float sap = 0.0f, san = 0.0f;
  #pragma unroll
  for (int k = lane; k < D; k += 64) {
    float a = emb[i * D + k];
    float dp = __fadd_rn(__fsub_rn(a, emb[pos * D + k]), EPS);
    float dn = __fadd_rn(__fsub_rn(a, emb[neg * D + k]), EPS);
    sap = fmaf(dp, dp, sap);
    san = fmaf(dn, dn, san);
  }
  #pragma unroll
  for (int off = 32; off > 0; off >>= 1) {
    sap += __shfl_down(sap, off);
    san += __shfl_down(san, off);
  }
  if (lane == 0) {
    int v = validf[i];
    float per = __fadd_rn(__fsub_rn(__fsqrt_rn(sap), __fsqrt_rn(san)), MARGIN);
    per = fmaxf(per, 0.0f);
    s_per[wid] = v ? per : 0.0f;
    s_cnt[wid] = v ? 1.0f : 0.0f;
  }
  __syncthreads();
  if (threadIdx.x == 0) {
    pers[blockIdx.x] = s_per[0] + s_per[1] + s_per[2] + s_per[3];
    cnts[blockIdx.x] = s_cnt[0] + s_cnt[1] + s_cnt[2] + s_cnt[3];
    __threadfence();
    uint32_t t = atomicAdd(ticket, 1u);
    s_last = (t == NPART - 1) ? 1 : 0;
  }
  __syncthreads();
  if (s_last) {                               // last block: final reduction
    __threadfence();
    volatile const float* vp = pers;
    volatile const float* vc = cnts;
    float sp = 0.0f, sc = 0.0f;
    for (int q = threadIdx.x; q < NPART; q += 256) { sp += vp[q]; sc += vc[q]; }
    #pragma unroll
    for (int off = 32; off > 0; off >>= 1) {
      sp += __shfl_down(sp, off);
      sc += __shfl_down(sc, off);
    }
    if (lane == 0) { s_rp[wid] = sp; s_rc[wid] = sc; }
    __syncthreads();
    if (threadIdx.x == 0) {
      float tp = s_rp[0] + s_rp[1] + s_rp[2] + s_rp[3];
      float tc = s_rc[0] + s_rc[1] + s_rc[2] + s_rc[3];
      out[0] = tp / fmaxf(tc, 1.0f);
    }
  }
}

extern "C" void kernel_launch(void* const* d_in, const int* in_sizes, int n_in,
                              void* d_out, int out_size, void* d_ws, size_t ws_size,
                              hipStream_t stream) {
  const float* emb = (const float*)d_in[0];
  const int* labels = (const int*)d_in[1];
  char* ws = (char*)d_ws;
  float* sq        = (float*)(ws + 0);          // 32 KB
  float* ap2lo     = (float*)(ws + 32768);      // 32 KB
  float* ap2hi     = (float*)(ws + 65536);      // 32 KB
  int* posx        = (int*)(ws + 98304);        // 32 KB
  int* validf      = (int*)(ws + 131072);       // 32 KB
  float* pers      = (float*)(ws + 163840);     // 8 KB
  float* cnts      = (float*)(ws + 172032);     // 8 KB
  uint32_t* semikey= (uint32_t*)(ws + 180224);  // 32 KB
  uint32_t* hardkey= (uint32_t*)(ws + 212992);  // 32 KB
  uint32_t* ticket = (uint32_t*)(ws + 245760);  // 4 B
  uint32_t* chnk   = (uint32_t*)(ws + 262144);  // 4 MB (total ~4.4 MB)
  float* out       = (float*)d_out;

  // jax.random.key(42) -> split
  uint32_t A0, B0, A1, B1;
  tf2x32(0u, 42u, 0u, 2u, A0, B0);
  tf2x32(0u, 42u, 1u, 3u, A1, B1);
  uint32_t kp0 = A0, kp1 = A1, kn0 = B0, kn1 = B1;

  pp_kernel<<<NPART, 256, 0, stream>>>(emb, labels, kp0, kp1, chnk, sq,
                                       posx, ap2lo, ap2hi, validf,
                                       semikey, hardkey, ticket);
  main_kernel<<<dim3(32, NCHUNK), 256, 0, stream>>>(chnk, labels, sq, ap2lo, ap2hi,
                                                    kn0, kn1, semikey, hardkey);
  finalize_kernel<<<NPART, 256, 0, stream>>>(emb, posx, validf, semikey, hardkey,
                                             pers, cnts, ticket, out);
}

// Round 10
// 167.697 us; speedup vs baseline: 1.2190x; 1.2190x over previous
//
#include <hip/hip_runtime.h>
#include <stdint.h>

#define B 8192
#define D 128
#define MARGIN 0.3f
#define EPS 1e-6f
#define HALFN (1u << 25)   // B*B/2 = 2^25
#define NCHUNK 64          // j-chunks for main kernel
#define JCH (B / NCHUNK)   // 128
#define NPART 2048         // finalize partial-sum blocks

using bf16x8 = __attribute__((ext_vector_type(8))) short;   // 8 bf16 = 4 VGPRs
using f32x16 = __attribute__((ext_vector_type(16))) float;  // MFMA 32x32 acc

// ---- Threefry-2x32 (JAX-compatible: 20 rounds, 5 key injections) ----
__host__ __device__ __forceinline__ void tf2x32(uint32_t k0, uint32_t k1,
                                                uint32_t x0, uint32_t x1,
                                                uint32_t& o0, uint32_t& o1) {
  uint32_t ks2 = k0 ^ k1 ^ 0x1BD11BDAu;
  uint32_t v0 = x0 + k0, v1 = x1 + k1;
#define RND(r) { v0 += v1; v1 = (v1 << (r)) | (v1 >> (32 - (r))); v1 ^= v0; }
  RND(13) RND(15) RND(26) RND(6)
  v0 += k1;  v1 += ks2 + 1u;
  RND(17) RND(29) RND(16) RND(24)
  v0 += ks2; v1 += k0 + 2u;
  RND(13) RND(15) RND(26) RND(6)
  v0 += k0;  v1 += k1 + 3u;
  RND(17) RND(29) RND(16) RND(24)
  v0 += k1;  v1 += ks2 + 4u;
  RND(13) RND(15) RND(26) RND(6)
  v0 += ks2; v1 += k0 + 5u;
#undef RND
  o0 = v0; o1 = v1;
}

// device rounds-only variant: caller pre-adds the key to the counter
// (v0 = x0 + k0, v1 = x1 + k1 hoisted as per-lane constants + j).
__device__ __forceinline__ void tf_rounds(uint32_t k0, uint32_t k1,
                                          uint32_t v0, uint32_t v1,
                                          uint32_t& o0, uint32_t& o1) {
  uint32_t ks2 = k0 ^ k1 ^ 0x1BD11BDAu;
#define RNDL(r) { v0 += v1; v1 = __builtin_rotateleft32(v1, r); v1 ^= v0; }
  RNDL(13) RNDL(15) RNDL(26) RNDL(6)
  v0 += k1;  v1 += ks2 + 1u;
  RNDL(17) RNDL(29) RNDL(16) RNDL(24)
  v0 += ks2; v1 += k0 + 2u;
  RNDL(13) RNDL(15) RNDL(26) RNDL(6)
  v0 += k0;  v1 += k1 + 3u;
  RNDL(17) RNDL(29) RNDL(16) RNDL(24)
  v0 += k1;  v1 += ks2 + 4u;
  RNDL(13) RNDL(15) RNDL(26) RNDL(6)
  v0 += ks2; v1 += k0 + 5u;
#undef RNDL
  o0 = v0; o1 = v1;
}

// gumbel-argmax reduces to integer compare on (bits >> 9) -- strictly monotone.
__device__ __forceinline__ uint32_t gbits(uint32_t k0, uint32_t k1, uint32_t f) {
  bool lo = f < HALFN;
  uint32_t x0 = lo ? f : f - HALFN;
  uint32_t x1 = lo ? f + HALFN : f;
  uint32_t o0, o1;
  tf2x32(k0, k1, x0, x1, o0, o1);
  return (lo ? o0 : o1) >> 9;
}

__device__ __forceinline__ uint16_t f2bf(float f) {   // RNE float->bf16
  uint32_t u = __float_as_uint(f);
  return (uint16_t)((u + 0x7FFFu + ((u >> 16) & 1u)) >> 16);
}
__device__ __forceinline__ float bf2f(uint16_t b) {
  return __uint_as_float((uint32_t)b << 16);
}
__device__ __forceinline__ bf16x8 as_bf(uint4 u) {
  union { uint4 a; bf16x8 b; } x; x.a = u; return x.b;
}

// ---- 1. split bf16 hi/lo into MFMA fragment-order chunks + row norms + key init ----
// chunk layout: [group g=row/32][kk=k/16][h=hi/lo][lane=(ksub<<5)|row%32] x 16B
__global__ __launch_bounds__(256) void prep_kernel(const float* __restrict__ emb,
                                                   uint32_t* __restrict__ chunk,
                                                   float* __restrict__ sq,
                                                   uint32_t* __restrict__ semikey,
                                                   uint32_t* __restrict__ hardkey) {
  int tid = blockIdx.x * 256 + threadIdx.x;   // 131072 total
  int row = tid >> 4, oct = tid & 15;
  const float* src = emb + row * D + oct * 8;
  uint32_t hi[4], lo[4];
  float s = 0.0f;
  #pragma unroll
  for (int e = 0; e < 4; e++) {
    float f0 = src[2 * e], f1 = src[2 * e + 1];
    s = fmaf(f0, f0, s); s = fmaf(f1, f1, s);
    uint16_t h0 = f2bf(f0), h1 = f2bf(f1);
    uint16_t l0 = f2bf(__fsub_rn(f0, bf2f(h0)));
    uint16_t l1 = f2bf(__fsub_rn(f1, bf2f(h1)));
    hi[e] = (uint32_t)h0 | ((uint32_t)h1 << 16);
    lo[e] = (uint32_t)l0 | ((uint32_t)l1 << 16);
  }
  // row-sum over the 16 threads sharing this row (xor masks stay in-group)
  s += __shfl_xor(s, 1); s += __shfl_xor(s, 2);
  s += __shfl_xor(s, 4); s += __shfl_xor(s, 8);
  if (oct == 0) { sq[row] = s; semikey[row] = 0u; hardkey[row] = 0xFFFFFFFFu; }
  int g = row >> 5, kk = oct >> 1, lane = ((oct & 1) << 5) | (row & 31);
  uint32_t base = ((g * 8 + kk) * 2) * 64 + lane;        // chunk index, h=0
  *(uint4*)&chunk[(size_t)base * 4]        = make_uint4(hi[0], hi[1], hi[2], hi[3]);
  *(uint4*)&chunk[(size_t)(base + 64) * 4] = make_uint4(lo[0], lo[1], lo[2], lo[3]);
}

// ---- 2. positive mining: block-cooperative label scan, then dense tf pass ----
// 256 threads scan the 8192-label array ONCE per block (vs once per wave),
// testing each j against the block's 4 anchor labels.
__global__ __launch_bounds__(256) void pos_kernel(
    const float* __restrict__ emb, const int* __restrict__ labels,
    const float* __restrict__ sq, uint32_t kp0, uint32_t kp1,
    int* __restrict__ posx, float* __restrict__ ap2lo, float* __restrict__ ap2hi,
    int* __restrict__ validf) {
  __shared__ int s_cnt[4];
  __shared__ int s_lab4[4];
  __shared__ int s_list[4][80];
  int wid = threadIdx.x >> 6, lane = threadIdx.x & 63;
  int i = blockIdx.x * 4 + wid;
  if (lane == 0) { s_cnt[wid] = 0; s_lab4[wid] = labels[i]; }
  __syncthreads();
  int l0 = s_lab4[0], l1 = s_lab4[1], l2 = s_lab4[2], l3 = s_lab4[3];
  #pragma unroll
  for (int it = 0; it < B / 1024; it++) {    // 8 iters, whole block covers 1024 j
    int j0 = it * 1024 + threadIdx.x * 4;
    int4 lv = *(const int4*)&labels[j0];
    #pragma unroll
    for (int e = 0; e < 4; e++) {
      int l = (&lv.x)[e];
      if (l == l0) { int pp = atomicAdd(&s_cnt[0], 1); if (pp < 80) s_list[0][pp] = j0 + e; }
      if (l == l1) { int pp = atomicAdd(&s_cnt[1], 1); if (pp < 80) s_list[1][pp] = j0 + e; }
      if (l == l2) { int pp = atomicAdd(&s_cnt[2], 1); if (pp < 80) s_list[2][pp] = j0 + e; }
      if (l == l3) { int pp = atomicAdd(&s_cnt[3], 1); if (pp < 80) s_list[3][pp] = j0 + e; }
    }
  }
  __syncthreads();
  int cnt = s_cnt[wid];

  // dense tf over ~16 candidates (list order random -> order-independent tie-break)
  uint32_t fbase = (uint32_t)i << 13;
  uint32_t bb = 0; int bi = -1;
  for (int t = lane; t < cnt; t += 64) {
    int j = s_list[wid][t];
    if (j != i) {
      uint32_t bits = gbits(kp0, kp1, fbase | (uint32_t)j);
      if (bi < 0 || bits > bb || (bits == bb && j < bi)) { bb = bits; bi = j; }
    }
  }
  #pragma unroll
  for (int off = 32; off > 0; off >>= 1) {
    uint32_t ob = __shfl_xor(bb, off);
    int oi = __shfl_xor(bi, off);
    if (oi >= 0 && (bi < 0 || ob > bb || (ob == bb && oi < bi))) { bb = ob; bi = oi; }
  }
  int pidx = (cnt >= 2) ? bi : 0;   // no positive -> argmax(-inf)=0

  float a0 = emb[i * D + lane],    a1 = emb[i * D + 64 + lane];
  float p0 = emb[pidx * D + lane], p1 = emb[pidx * D + 64 + lane];
  float dot = fmaf(a1, p1, a0 * p0);
  #pragma unroll
  for (int off = 32; off > 0; off >>= 1) dot += __shfl_xor(dot, off);

  if (lane == 0) {
    float d2 = __fadd_rn(__fsub_rn(sq[pidx], __fmul_rn(2.0f, dot)), sq[i]);
    float apv = __fsqrt_rn(fmaxf(d2, 0.0f));
    float apm = __fadd_rn(apv, MARGIN);
    ap2lo[i] = __fmul_rn(apv, apv);           // band test in d^2 domain
    ap2hi[i] = __fmul_rn(apm, apm);
    posx[i] = pidx;
    validf[i] = (cnt >= 2 && cnt < B) ? 1 : 0;
  }
}

// ---- 3. main: swapped-operand MFMA + register-local mining, u32 keys ----
// grid (32 anchor-blocks, 64 j-chunks) x 256 thr -> 2048 blocks (8-deep/CU
// queue smooths barrier stalls; measured 101 us, VALUBusy 80%).
// __launch_bounds__(256,3): the (256,4)=128-reg cap spilled TWICE (R5, R7:
// scratch FETCH 146 MB, VALUBusy 58%); this kernel needs the 170-reg budget.
// Xb = fma(-2, dot, sq[j]+4) > 0 is simultaneously the band-test value
// (vs per-lane pre-shifted thresholds) and bit-monotone hard-min key.
// semi key: (o & 0xFFFFE000)|(8191-j), v_max_u32 merge (0 = none).
// hard key: (Xbits & ~8191) | j, v_min_u32 merge (~0 = none).
__global__ __launch_bounds__(256, 3) void main_kernel(
    const uint32_t* __restrict__ chunk, const int* __restrict__ labels,
    const float* __restrict__ sq, const float* __restrict__ ap2lo,
    const float* __restrict__ ap2hi, uint32_t kn0, uint32_t kn1,
    uint32_t* __restrict__ semikey, uint32_t* __restrict__ hardkey) {
  __shared__ uint32_t ldsB[8192];   // 32 KB: [n0][kk][h][lane] 16B chunks (j rows)
  __shared__ float2 s_ji[64];       // .x = sq[j]+4, .y = as_float(label[j])

  const int tid = threadIdx.x;
  const int w = tid >> 6, lane = tid & 63;
  const int p = lane & 31, khalf = lane >> 5;
  const int A0 = blockIdx.x * 128;
  const int jc = blockIdx.y;
  const int ia_lo = A0 + 32 * w + p;
  const int ia_up = ia_lo + 4096;

  // anchor B-frags (hi only): 2 tiles x 8 ksteps = 16 x 16B = 64 VGPRs
  bf16x8 Af[2][8];
  {
    int g_lo = (A0 >> 5) + w;
    #pragma unroll
    for (int m = 0; m < 2; m++) {
      int g = g_lo + (m ? 128 : 0);
      #pragma unroll
      for (int kk = 0; kk < 8; kk++)
        Af[m][kk] = as_bf(*(const uint4*)&chunk[(size_t)(((g * 8 + kk) * 2) * 64 + lane) * 4]);
    }
  }

  const int lab_lo = labels[ia_lo], lab_up = labels[ia_up];
  const float sq_lo = sq[ia_lo], sq_up = sq[ia_up];
  // pre-shifted band thresholds in Xb domain (Xb = d2 - sq_anchor + 4)
  const float Xlo_lo = __fadd_rn(__fsub_rn(ap2lo[ia_lo], sq_lo), 4.0f);
  const float Xhi_lo = __fadd_rn(__fsub_rn(ap2hi[ia_lo], sq_lo), 4.0f);
  const float Xlo_up = __fadd_rn(__fsub_rn(ap2lo[ia_up], sq_up), 4.0f);
  const float Xhi_up = __fadd_rn(__fsub_rn(ap2hi[ia_up], sq_up), 4.0f);
  // hoisted threefry counter bases: v0 = c0 + j, v1 = c1 + j
  const uint32_t c0 = ((uint32_t)ia_lo << 13) + kn0;
  const uint32_t c1 = ((uint32_t)ia_lo << 13) + HALFN + kn1;
  uint32_t sk_lo = 0u, sk_up = 0u;
  uint32_t hk_lo = 0xFFFFFFFFu, hk_up = 0xFFFFFFFFu;

  for (int jt = 0; jt < JCH; jt += 64) {    // 2 j-tiles
    const int jb = jc * JCH + jt;
    __syncthreads();
    {
      const uint32_t* src = chunk + (size_t)(jb >> 5) * 4096;  // 2 groups = 8192 dwords
      #pragma unroll
      for (int q = 0; q < 8; q++) {
        int idx = tid + 256 * q;
        *(uint4*)&ldsB[idx * 4] = *(const uint4*)&src[idx * 4];
      }
      if (tid < 64)
        s_ji[tid] = make_float2(sq[jb + tid] + 4.0f, __int_as_float(labels[jb + tid]));
    }
    __syncthreads();

    #pragma unroll
    for (int n0 = 0; n0 < 2; n0++) {
      f32x16 acc[2];   // [m = anchor tile lo/up] -- reused across n0 (reg pressure)
      acc[0] = (f32x16)(0.0f);
      acc[1] = (f32x16)(0.0f);

      #pragma unroll
      for (int kk = 0; kk < 8; kk++) {
        bf16x8 jh = *(const bf16x8*)&ldsB[(size_t)((n0 * 16 + kk * 2 + 0) * 64 + lane) * 4];
        bf16x8 jl = *(const bf16x8*)&ldsB[(size_t)((n0 * 16 + kk * 2 + 1) * 64 + lane) * 4];
        acc[0] = __builtin_amdgcn_mfma_f32_32x32x16_bf16(jh, Af[0][kk], acc[0], 0, 0, 0);
        acc[0] = __builtin_amdgcn_mfma_f32_32x32x16_bf16(jl, Af[0][kk], acc[0], 0, 0, 0);
        acc[1] = __builtin_amdgcn_mfma_f32_32x32x16_bf16(jh, Af[1][kk], acc[1], 0, 0, 0);
        acc[1] = __builtin_amdgcn_mfma_f32_32x32x16_bf16(jl, Af[1][kk], acc[1], 0, 0, 0);
      }

      // mining epilogue: groups of 4 j's -> 4 independent threefry chains (ILP)
      #pragma unroll
      for (int g = 0; g < 4; g++) {
        uint32_t olo[4], oup[4];
        #pragma unroll
        for (int t = 0; t < 4; t++) {
          int row = t + (g << 3) + (khalf << 2);
          uint32_t jv = (uint32_t)(jb + n0 * 32 + row);
          tf_rounds(kn0, kn1, c0 + jv, c1 + jv, olo[t], oup[t]);  // o0->i, o1->i+4096
        }
        #pragma unroll
        for (int t = 0; t < 4; t++) {
          int r = (g << 2) + t;
          int row = t + (g << 3) + (khalf << 2);
          int jl_ = n0 * 32 + row;
          int j = jb + jl_;
          float2 ji = s_ji[jl_];
          int lj = __float_as_int(ji.y);
          float Xl = fmaf(-2.0f, acc[0][r], ji.x);
          float Xu = fmaf(-2.0f, acc[1][r], ji.x);
          bool nl = (lj != lab_lo), nu = (lj != lab_up);
          uint32_t rj = (uint32_t)(8191 - j);
          uint32_t keyl = (olo[t] & 0xFFFFE000u) | rj;   // == (bits19<<13)|rj
          uint32_t keyu = (oup[t] & 0xFFFFE000u) | rj;
          bool il = nl && (Xl > Xlo_lo) && (Xl < Xhi_lo);
          bool iu = nu && (Xu > Xlo_up) && (Xu < Xhi_up);
          uint32_t csl = il ? keyl : 0u;
          uint32_t csu = iu ? keyu : 0u;
          sk_lo = max(sk_lo, csl);
          sk_up = max(sk_up, csu);
          uint32_t hl = nl ? ((__float_as_uint(Xl) & 0xFFFFE000u) | (uint32_t)j) : 0xFFFFFFFFu;
          uint32_t hu = nu ? ((__float_as_uint(Xu) & 0xFFFFE000u) | (uint32_t)j) : 0xFFFFFFFFu;
          hk_lo = min(hk_lo, hl);
          hk_up = min(hk_up, hu);
        }
      }
    }
  }

  // merge khalf halves (lane ^ 32 holds same anchor pair, other j-rows)
  {
    uint32_t o;
    o = __shfl_xor(sk_lo, 32); sk_lo = max(sk_lo, o);
    o = __shfl_xor(sk_up, 32); sk_up = max(sk_up, o);
    o = __shfl_xor(hk_lo, 32); hk_lo = min(hk_lo, o);
    o = __shfl_xor(hk_up, 32); hk_up = min(hk_up, o);
  }
  if (lane < 32) {
    atomicMax(&semikey[ia_lo], sk_lo);
    atomicMin(&hardkey[ia_lo], hk_lo);
  } else {
    atomicMax(&semikey[ia_up], sk_up);
    atomicMin(&hardkey[ia_up], hk_up);
  }
}

// ---- 4. triplet loss -> per-block partials (no same-address atomics) ----
__global__ __launch_bounds__(256) void finalize_kernel(
    const float* __restrict__ emb, const int* __restrict__ posx,
    const int* __restrict__ validf,
    const uint32_t* __restrict__ semikey, const uint32_t* __restrict__ hardkey,
    float* __restrict__ pers, float* __restrict__ cnts) {
  __shared__ float s_per[4];
  __shared__ float s_cnt[4];
  int wid = threadIdx.x >> 6, lane = threadIdx.x & 63;
  int i = blockIdx.x * 4 + wid;

  uint32_t sk = semikey[i];
  uint32_t hk = hardkey[i];
  int neg = sk ? (8191 - (int)(sk & 8191u)) : (int)(hk & 8191u);
  if (!sk && hk == 0xFFFFFFFFu) neg = 0;    // no negatives at all (masked by valid)
  int pos = posx[i];

  float sap = 0.0f, san = 0.0f;
  #pragma unroll
  for (int k = lane; k < D; k += 64) {
    float a = emb[i * D + k];
    float dp = __fadd_rn(__fsub_rn(a, emb[pos * D + k]), EPS);
    float dn = __fadd_rn(__fsub_rn(a, emb[neg * D + k]), EPS);
    sap = fmaf(dp, dp, sap);
    san = fmaf(dn, dn, san);
  }
  #pragma unroll
  for (int off = 32; off > 0; off >>= 1) {
    sap += __shfl_down(sap, off);
    san += __shfl_down(san, off);
  }
  if (lane == 0) {
    int v = validf[i];
    float per = __fadd_rn(__fsub_rn(__fsqrt_rn(sap), __fsqrt_rn(san)), MARGIN);
    per = fmaxf(per, 0.0f);
    s_per[wid] = v ? per : 0.0f;
    s_cnt[wid] = v ? 1.0f : 0.0f;
  }
  __syncthreads();
  if (threadIdx.x == 0) {
    pers[blockIdx.x] = s_per[0] + s_per[1] + s_per[2] + s_per[3];
    cnts[blockIdx.x] = s_cnt[0] + s_cnt[1] + s_cnt[2] + s_cnt[3];
  }
}

// ---- 5. reduce partials -> final loss ----
__global__ __launch_bounds__(256) void reduce_kernel(
    const float* __restrict__ pers, const float* __restrict__ cnts,
    float* __restrict__ out) {
  __shared__ float rp[256], rcn[256];
  int tid = threadIdx.x;
  float sp = 0.0f, sc = 0.0f;
  #pragma unroll
  for (int q = 0; q < NPART / 256; q++) {
    sp += pers[tid + 256 * q];
    sc += cnts[tid + 256 * q];
  }
  rp[tid] = sp; rcn[tid] = sc;
  __syncthreads();
  for (int s = 128; s > 0; s >>= 1) {
    if (tid < s) { rp[tid] += rp[tid + s]; rcn[tid] += rcn[tid + s]; }
    __syncthreads();
  }
  if (tid == 0) out[0] = rp[0] / fmaxf(rcn[0], 1.0f);
}

extern "C" void kernel_launch(void* const* d_in, const int* in_sizes, int n_in,
                              void* d_out, int out_size, void* d_ws, size_t ws_size,
                              hipStream_t stream) {
  const float* emb = (const float*)d_in[0];
  const int* labels = (const int*)d_in[1];
  char* ws = (char*)d_ws;
  float* sq        = (float*)(ws + 0);          // 32 KB
  float* ap2lo     = (float*)(ws + 32768);      // 32 KB
  float* ap2hi     = (float*)(ws + 65536);      // 32 KB
  int* posx        = (int*)(ws + 98304);        // 32 KB
  int* validf      = (int*)(ws + 131072);       // 32 KB
  float* pers      = (float*)(ws + 163840);     // 8 KB
  float* cnts      = (float*)(ws + 172032);     // 8 KB
  uint32_t* semikey= (uint32_t*)(ws + 180224);  // 32 KB
  uint32_t* hardkey= (uint32_t*)(ws + 212992);  // 32 KB
  uint32_t* chnk   = (uint32_t*)(ws + 262144);  // 4 MB (total ~4.4 MB)
  float* out       = (float*)d_out;

  // jax.random.key(42) -> split
  uint32_t A0, B0, A1, B1;
  tf2x32(0u, 42u, 0u, 2u, A0, B0);
  tf2x32(0u, 42u, 1u, 3u, A1, B1);
  uint32_t kp0 = A0, kp1 = A1, kn0 = B0, kn1 = B1;

  prep_kernel<<<512, 256, 0, stream>>>(emb, chnk, sq, semikey, hardkey);
  pos_kernel<<<B / 4, 256, 0, stream>>>(emb, labels, sq, kp0, kp1, posx, ap2lo, ap2hi, validf);
  main_kernel<<<dim3(32, NCHUNK), 256, 0, stream>>>(chnk, labels, sq, ap2lo, ap2hi,
                                                    kn0, kn1, semikey, hardkey);
  finalize_kernel<<<NPART, 256, 0, stream>>>(emb, posx, validf, semikey, hardkey,
                                             pers, cnts);
  reduce_kernel<<<1, 256, 0, stream>>>(pers, cnts, out);
}

// Round 11
// 163.099 us; speedup vs baseline: 1.2533x; 1.0282x over previous
//
#include <hip/hip_runtime.h>
#include <stdint.h>

#define B 8192
#define D 128
#define MARGIN 0.3f
#define EPS 1e-6f
#define HALFN (1u << 25)   // B*B/2 = 2^25
#define NCHUNK 64          // j-chunks for main kernel
#define JCH (B / NCHUNK)   // 128
#define NPART 2048         // finalize partial-sum blocks

using bf16x8 = __attribute__((ext_vector_type(8))) short;   // 8 bf16 = 4 VGPRs
using f32x16 = __attribute__((ext_vector_type(16))) float;  // MFMA 32x32 acc

// ---- Threefry-2x32 (JAX-compatible: 20 rounds, 5 key injections) ----
__host__ __device__ __forceinline__ void tf2x32(uint32_t k0, uint32_t k1,
                                                uint32_t x0, uint32_t x1,
                                                uint32_t& o0, uint32_t& o1) {
  uint32_t ks2 = k0 ^ k1 ^ 0x1BD11BDAu;
  uint32_t v0 = x0 + k0, v1 = x1 + k1;
#define RND(r) { v0 += v1; v1 = (v1 << (r)) | (v1 >> (32 - (r))); v1 ^= v0; }
  RND(13) RND(15) RND(26) RND(6)
  v0 += k1;  v1 += ks2 + 1u;
  RND(17) RND(29) RND(16) RND(24)
  v0 += ks2; v1 += k0 + 2u;
  RND(13) RND(15) RND(26) RND(6)
  v0 += k0;  v1 += k1 + 3u;
  RND(17) RND(29) RND(16) RND(24)
  v0 += k1;  v1 += ks2 + 4u;
  RND(13) RND(15) RND(26) RND(6)
  v0 += ks2; v1 += k0 + 5u;
#undef RND
  o0 = v0; o1 = v1;
}

// device rounds-only variant: caller pre-adds the key to the counter
// (v0 = x0 + k0, v1 = x1 + k1 hoisted as per-lane constants + j).
__device__ __forceinline__ void tf_rounds(uint32_t k0, uint32_t k1,
                                          uint32_t v0, uint32_t v1,
                                          uint32_t& o0, uint32_t& o1) {
  uint32_t ks2 = k0 ^ k1 ^ 0x1BD11BDAu;
#define RNDL(r) { v0 += v1; v1 = __builtin_rotateleft32(v1, r); v1 ^= v0; }
  RNDL(13) RNDL(15) RNDL(26) RNDL(6)
  v0 += k1;  v1 += ks2 + 1u;
  RNDL(17) RNDL(29) RNDL(16) RNDL(24)
  v0 += ks2; v1 += k0 + 2u;
  RNDL(13) RNDL(15) RNDL(26) RNDL(6)
  v0 += k0;  v1 += k1 + 3u;
  RNDL(17) RNDL(29) RNDL(16) RNDL(24)
  v0 += k1;  v1 += ks2 + 4u;
  RNDL(13) RNDL(15) RNDL(26) RNDL(6)
  v0 += ks2; v1 += k0 + 5u;
#undef RNDL
  o0 = v0; o1 = v1;
}

// gumbel-argmax reduces to integer compare on (bits >> 9) -- strictly monotone.
__device__ __forceinline__ uint32_t gbits(uint32_t k0, uint32_t k1, uint32_t f) {
  bool lo = f < HALFN;
  uint32_t x0 = lo ? f : f - HALFN;
  uint32_t x1 = lo ? f + HALFN : f;
  uint32_t o0, o1;
  tf2x32(k0, k1, x0, x1, o0, o1);
  return (lo ? o0 : o1) >> 9;
}

__device__ __forceinline__ uint16_t f2bf(float f) {   // RNE float->bf16
  uint32_t u = __float_as_uint(f);
  return (uint16_t)((u + 0x7FFFu + ((u >> 16) & 1u)) >> 16);
}
__device__ __forceinline__ float bf2f(uint16_t b) {
  return __uint_as_float((uint32_t)b << 16);
}
__device__ __forceinline__ bf16x8 as_bf(uint4 u) {
  union { uint4 a; bf16x8 b; } x; x.a = u; return x.b;
}

// ---- 1. fused prep + positive mining (NO cross-block tickets -- R9 lesson) ----
// 2048 blocks. All blocks: block-cooperative label scan + dense tf positive
// pick for 4 anchors (inline norms -> no dependency on prep outputs).
// Blocks < 512 additionally do the bf16 hi/lo chunk split + row norms + key
// init (consumed only by the LATER main launch).
__global__ __launch_bounds__(256) void pp_kernel(
    const float* __restrict__ emb, const int* __restrict__ labels,
    uint32_t kp0, uint32_t kp1,
    uint32_t* __restrict__ chunk, float* __restrict__ sq,
    int* __restrict__ posx, float* __restrict__ ap2lo, float* __restrict__ ap2hi,
    int* __restrict__ validf,
    uint32_t* __restrict__ semikey, uint32_t* __restrict__ hardkey) {
  __shared__ int s_cnt[4];
  __shared__ int s_lab4[4];
  __shared__ int s_list[4][80];
  int wid = threadIdx.x >> 6, lane = threadIdx.x & 63;
  int i = blockIdx.x * 4 + wid;
  if (lane == 0) { s_cnt[wid] = 0; s_lab4[wid] = labels[i]; }

  // ---- prep phase (chunk: [g=row/32][kk=k/16][h][lane=(ksub<<5)|row%32] x16B) ----
  if (blockIdx.x < 512) {
    int tid = blockIdx.x * 256 + threadIdx.x;   // 131072 total
    int row = tid >> 4, oct = tid & 15;
    const float* src = emb + row * D + oct * 8;
    uint32_t hi[4], lo[4];
    float s = 0.0f;
    #pragma unroll
    for (int e = 0; e < 4; e++) {
      float f0 = src[2 * e], f1 = src[2 * e + 1];
      s = fmaf(f0, f0, s); s = fmaf(f1, f1, s);
      uint16_t h0 = f2bf(f0), h1 = f2bf(f1);
      uint16_t l0 = f2bf(__fsub_rn(f0, bf2f(h0)));
      uint16_t l1 = f2bf(__fsub_rn(f1, bf2f(h1)));
      hi[e] = (uint32_t)h0 | ((uint32_t)h1 << 16);
      lo[e] = (uint32_t)l0 | ((uint32_t)l1 << 16);
    }
    s += __shfl_xor(s, 1); s += __shfl_xor(s, 2);
    s += __shfl_xor(s, 4); s += __shfl_xor(s, 8);
    if (oct == 0) { sq[row] = s; semikey[row] = 0u; hardkey[row] = 0xFFFFFFFFu; }
    int g = row >> 5, kk = oct >> 1, ln = ((oct & 1) << 5) | (row & 31);
    uint32_t base = ((g * 8 + kk) * 2) * 64 + ln;        // chunk index, h=0
    *(uint4*)&chunk[(size_t)base * 4]        = make_uint4(hi[0], hi[1], hi[2], hi[3]);
    *(uint4*)&chunk[(size_t)(base + 64) * 4] = make_uint4(lo[0], lo[1], lo[2], lo[3]);
  }

  // ---- pos phase: block-cooperative label scan, then dense tf pass ----
  __syncthreads();
  int l0 = s_lab4[0], l1 = s_lab4[1], l2 = s_lab4[2], l3 = s_lab4[3];
  #pragma unroll
  for (int it = 0; it < B / 1024; it++) {    // 8 iters, whole block covers 1024 j
    int j0 = it * 1024 + threadIdx.x * 4;
    int4 lv = *(const int4*)&labels[j0];
    #pragma unroll
    for (int e = 0; e < 4; e++) {
      int l = (&lv.x)[e];
      if (l == l0) { int pp = atomicAdd(&s_cnt[0], 1); if (pp < 80) s_list[0][pp] = j0 + e; }
      if (l == l1) { int pp = atomicAdd(&s_cnt[1], 1); if (pp < 80) s_list[1][pp] = j0 + e; }
      if (l == l2) { int pp = atomicAdd(&s_cnt[2], 1); if (pp < 80) s_list[2][pp] = j0 + e; }
      if (l == l3) { int pp = atomicAdd(&s_cnt[3], 1); if (pp < 80) s_list[3][pp] = j0 + e; }
    }
  }
  __syncthreads();
  int cnt = s_cnt[wid];

  // dense tf over ~16 candidates (list order random -> order-independent tie-break)
  uint32_t fbase = (uint32_t)i << 13;
  uint32_t bb = 0; int bi = -1;
  for (int t = lane; t < cnt; t += 64) {
    int j = s_list[wid][t];
    if (j != i) {
      uint32_t bits = gbits(kp0, kp1, fbase | (uint32_t)j);
      if (bi < 0 || bits > bb || (bits == bb && j < bi)) { bb = bits; bi = j; }
    }
  }
  #pragma unroll
  for (int off = 32; off > 0; off >>= 1) {
    uint32_t ob = __shfl_xor(bb, off);
    int oi = __shfl_xor(bi, off);
    if (oi >= 0 && (bi < 0 || ob > bb || (ob == bb && oi < bi))) { bb = ob; bi = oi; }
  }
  int pidx = (cnt >= 2) ? bi : 0;   // no positive -> argmax(-inf)=0

  float a0 = emb[i * D + lane],    a1 = emb[i * D + 64 + lane];
  float p0 = emb[pidx * D + lane], p1 = emb[pidx * D + 64 + lane];
  float dot = fmaf(a1, p1, a0 * p0);
  float sqi = fmaf(a1, a1, a0 * a0);
  float sqp = fmaf(p1, p1, p0 * p0);
  #pragma unroll
  for (int off = 32; off > 0; off >>= 1) {
    dot += __shfl_xor(dot, off);
    sqi += __shfl_xor(sqi, off);
    sqp += __shfl_xor(sqp, off);
  }

  if (lane == 0) {
    float d2 = __fadd_rn(__fsub_rn(sqp, __fmul_rn(2.0f, dot)), sqi);
    float apv = __fsqrt_rn(fmaxf(d2, 0.0f));
    float apm = __fadd_rn(apv, MARGIN);
    ap2lo[i] = __fmul_rn(apv, apv);           // band test in d^2 domain
    ap2hi[i] = __fmul_rn(apm, apm);
    posx[i] = pidx;
    validf[i] = (cnt >= 2 && cnt < B) ? 1 : 0;
  }
}

// ---- 2. main: swapped-operand MFMA + register-local mining, u32 keys ----
// grid (32 anchor-blocks, 64 j-chunks) x 256 thr -> 2048 blocks (8-deep/CU
// queue smooths barrier stalls; best measured 101 us, VALUBusy 80%).
// __launch_bounds__(256,3): the (256,4)=128-reg cap spilled TWICE (R5, R7:
// scratch FETCH 146 MB, VALUBusy 58%); this kernel needs the 170-reg budget.
// Xb = fma(-2, dot, sq[j]+4) > 0 is simultaneously the band-test value
// (vs per-lane pre-shifted thresholds) and bit-monotone hard-min key.
// semi key: (o & 0xFFFFE000)|(8191-j), v_max_u32 merge (0 = none).
// hard key: (Xbits & ~8191) | j, v_min_u32 merge (~0 = none).
__global__ __launch_bounds__(256, 3) void main_kernel(
    const uint32_t* __restrict__ chunk, const int* __restrict__ labels,
    const float* __restrict__ sq, const float* __restrict__ ap2lo,
    const float* __restrict__ ap2hi, uint32_t kn0, uint32_t kn1,
    uint32_t* __restrict__ semikey, uint32_t* __restrict__ hardkey) {
  __shared__ uint32_t ldsB[8192];   // 32 KB: [n0][kk][h][lane] 16B chunks (j rows)
  __shared__ float2 s_ji[64];       // .x = sq[j]+4, .y = as_float(label[j])

  const int tid = threadIdx.x;
  const int w = tid >> 6, lane = tid & 63;
  const int p = lane & 31, khalf = lane >> 5;
  const int A0 = blockIdx.x * 128;
  const int jc = blockIdx.y;
  const int ia_lo = A0 + 32 * w + p;
  const int ia_up = ia_lo + 4096;

  // anchor B-frags (hi only): 2 tiles x 8 ksteps = 16 x 16B = 64 VGPRs
  bf16x8 Af[2][8];
  {
    int g_lo = (A0 >> 5) + w;
    #pragma unroll
    for (int m = 0; m < 2; m++) {
      int g = g_lo + (m ? 128 : 0);
      #pragma unroll
      for (int kk = 0; kk < 8; kk++)
        Af[m][kk] = as_bf(*(const uint4*)&chunk[(size_t)(((g * 8 + kk) * 2) * 64 + lane) * 4]);
    }
  }

  const int lab_lo = labels[ia_lo], lab_up = labels[ia_up];
  const float sq_lo = sq[ia_lo], sq_up = sq[ia_up];
  // pre-shifted band thresholds in Xb domain (Xb = d2 - sq_anchor + 4)
  const float Xlo_lo = __fadd_rn(__fsub_rn(ap2lo[ia_lo], sq_lo), 4.0f);
  const float Xhi_lo = __fadd_rn(__fsub_rn(ap2hi[ia_lo], sq_lo), 4.0f);
  const float Xlo_up = __fadd_rn(__fsub_rn(ap2lo[ia_up], sq_up), 4.0f);
  const float Xhi_up = __fadd_rn(__fsub_rn(ap2hi[ia_up], sq_up), 4.0f);
  // hoisted threefry counter bases: v0 = c0 + j, v1 = c1 + j
  const uint32_t c0 = ((uint32_t)ia_lo << 13) + kn0;
  const uint32_t c1 = ((uint32_t)ia_lo << 13) + HALFN + kn1;
  uint32_t sk_lo = 0u, sk_up = 0u;
  uint32_t hk_lo = 0xFFFFFFFFu, hk_up = 0xFFFFFFFFu;

  for (int jt = 0; jt < JCH; jt += 64) {    // 2 j-tiles
    const int jb = jc * JCH + jt;
    __syncthreads();
    {
      const uint32_t* src = chunk + (size_t)(jb >> 5) * 4096;  // 2 groups = 8192 dwords
      #pragma unroll
      for (int q = 0; q < 8; q++) {
        int idx = tid + 256 * q;
        *(uint4*)&ldsB[idx * 4] = *(const uint4*)&src[idx * 4];
      }
      if (tid < 64)
        s_ji[tid] = make_float2(sq[jb + tid] + 4.0f, __int_as_float(labels[jb + tid]));
    }
    __syncthreads();

    #pragma unroll
    for (int n0 = 0; n0 < 2; n0++) {
      f32x16 acc[2];   // [m = anchor tile lo/up] -- reused across n0 (reg pressure)
      acc[0] = (f32x16)(0.0f);
      acc[1] = (f32x16)(0.0f);

      #pragma unroll
      for (int kk = 0; kk < 8; kk++) {
        bf16x8 jh = *(const bf16x8*)&ldsB[(size_t)((n0 * 16 + kk * 2 + 0) * 64 + lane) * 4];
        bf16x8 jl = *(const bf16x8*)&ldsB[(size_t)((n0 * 16 + kk * 2 + 1) * 64 + lane) * 4];
        acc[0] = __builtin_amdgcn_mfma_f32_32x32x16_bf16(jh, Af[0][kk], acc[0], 0, 0, 0);
        acc[0] = __builtin_amdgcn_mfma_f32_32x32x16_bf16(jl, Af[0][kk], acc[0], 0, 0, 0);
        acc[1] = __builtin_amdgcn_mfma_f32_32x32x16_bf16(jh, Af[1][kk], acc[1], 0, 0, 0);
        acc[1] = __builtin_amdgcn_mfma_f32_32x32x16_bf16(jl, Af[1][kk], acc[1], 0, 0, 0);
      }

      // mining epilogue: groups of 4 j's -> 4 independent threefry chains (ILP)
      #pragma unroll
      for (int g = 0; g < 4; g++) {
        uint32_t olo[4], oup[4];
        #pragma unroll
        for (int t = 0; t < 4; t++) {
          int row = t + (g << 3) + (khalf << 2);
          uint32_t jv = (uint32_t)(jb + n0 * 32 + row);
          tf_rounds(kn0, kn1, c0 + jv, c1 + jv, olo[t], oup[t]);  // o0->i, o1->i+4096
        }
        #pragma unroll
        for (int t = 0; t < 4; t++) {
          int r = (g << 2) + t;
          int row = t + (g << 3) + (khalf << 2);
          int jl_ = n0 * 32 + row;
          int j = jb + jl_;
          float2 ji = s_ji[jl_];
          int lj = __float_as_int(ji.y);
          float Xl = fmaf(-2.0f, acc[0][r], ji.x);
          float Xu = fmaf(-2.0f, acc[1][r], ji.x);
          bool nl = (lj != lab_lo), nu = (lj != lab_up);
          uint32_t rj = (uint32_t)(8191 - j);
          uint32_t keyl = (olo[t] & 0xFFFFE000u) | rj;   // == (bits19<<13)|rj
          uint32_t keyu = (oup[t] & 0xFFFFE000u) | rj;
          bool il = nl && (Xl > Xlo_lo) && (Xl < Xhi_lo);
          bool iu = nu && (Xu > Xlo_up) && (Xu < Xhi_up);
          uint32_t csl = il ? keyl : 0u;
          uint32_t csu = iu ? keyu : 0u;
          sk_lo = max(sk_lo, csl);
          sk_up = max(sk_up, csu);
          uint32_t hl = nl ? ((__float_as_uint(Xl) & 0xFFFFE000u) | (uint32_t)j) : 0xFFFFFFFFu;
          uint32_t hu = nu ? ((__float_as_uint(Xu) & 0xFFFFE000u) | (uint32_t)j) : 0xFFFFFFFFu;
          hk_lo = min(hk_lo, hl);
          hk_up = min(hk_up, hu);
        }
      }
    }
  }

  // merge khalf halves (lane ^ 32 holds same anchor pair, other j-rows)
  {
    uint32_t o;
    o = __shfl_xor(sk_lo, 32); sk_lo = max(sk_lo, o);
    o = __shfl_xor(sk_up, 32); sk_up = max(sk_up, o);
    o = __shfl_xor(hk_lo, 32); hk_lo = min(hk_lo, o);
    o = __shfl_xor(hk_up, 32); hk_up = min(hk_up, o);
  }
  if (lane < 32) {
    atomicMax(&semikey[ia_lo], sk_lo);
    atomicMin(&hardkey[ia_lo], hk_lo);
  } else {
    atomicMax(&semikey[ia_up], sk_up);
    atomicMin(&hardkey[ia_up], hk_up);
  }
}

// ---- 3. triplet loss -> per-block partials (no same-address atomics) ----
__global__ __launch_bounds__(256) void finalize_kernel(
    const float* __restrict__ emb, const int* __restrict__ posx,
    const int* __restrict__ validf,
    const uint32_t* __restrict__ semikey, const uint32_t* __restrict__ hardkey,
    float* __restrict__ pers, float* __restrict__ cnts) {
  __shared__ float s_per[4];
  __shared__ float s_cnt[4];
  int wid = threadIdx.x >> 6, lane = threadIdx.x & 63;
  int i = blockIdx.x * 4 + wid;

  uint32_t sk = semikey[i];
  uint32_t hk = hardkey[i];
  int neg = sk ? (8191 - (int)(sk & 8191u)) : (int)(hk & 8191u);
  if (!sk && hk == 0xFFFFFFFFu) neg = 0;    // no negatives at all (masked by valid)
  int pos = posx[i];

  float sap = 0.0f, san = 0.0f;
  #pragma unroll
  for (int k = lane; k < D; k += 64) {
    float a = emb[i * D + k];
    float dp = __fadd_rn(__fsub_rn(a, emb[pos * D + k]), EPS);
    float dn = __fadd_rn(__fsub_rn(a, emb[neg * D + k]), EPS);
    sap = fmaf(dp, dp, sap);
    san = fmaf(dn, dn, san);
  }
  #pragma unroll
  for (int off = 32; off > 0; off >>= 1) {
    sap += __shfl_down(sap, off);
    san += __shfl_down(san, off);
  }
  if (lane == 0) {
    int v = validf[i];
    float per = __fadd_rn(__fsub_rn(__fsqrt_rn(sap), __fsqrt_rn(san)), MARGIN);
    per = fmaxf(per, 0.0f);
    s_per[wid] = v ? per : 0.0f;
    s_cnt[wid] = v ? 1.0f : 0.0f;
  }
  __syncthreads();
  if (threadIdx.x == 0) {
    pers[blockIdx.x] = s_per[0] + s_per[1] + s_per[2] + s_per[3];
    cnts[blockIdx.x] = s_cnt[0] + s_cnt[1] + s_cnt[2] + s_cnt[3];
  }
}

// ---- 4. reduce partials -> final loss ----
__global__ __launch_bounds__(256) void reduce_kernel(
    const float* __restrict__ pers, const float* __restrict__ cnts,
    float* __restrict__ out) {
  __shared__ float rp[256], rcn[256];
  int tid = threadIdx.x;
  float sp = 0.0f, sc = 0.0f;
  #pragma unroll
  for (int q = 0; q < NPART / 256; q++) {
    sp += pers[tid + 256 * q];
    sc += cnts[tid + 256 * q];
  }
  rp[tid] = sp; rcn[tid] = sc;
  __syncthreads();
  for (int s = 128; s > 0; s >>= 1) {
    if (tid < s) { rp[tid] += rp[tid + s]; rcn[tid] += rcn[tid + s]; }
    __syncthreads();
  }
  if (tid == 0) out[0] = rp[0] / fmaxf(rcn[0], 1.0f);
}

extern "C" void kernel_launch(void* const* d_in, const int* in_sizes, int n_in,
                              void* d_out, int out_size, void* d_ws, size_t ws_size,
                              hipStream_t stream) {
  const float* emb = (const float*)d_in[0];
  const int* labels = (const int*)d_in[1];
  char* ws = (char*)d_ws;
  float* sq        = (float*)(ws + 0);          // 32 KB
  float* ap2lo     = (float*)(ws + 32768);      // 32 KB
  float* ap2hi     = (float*)(ws + 65536);      // 32 KB
  int* posx        = (int*)(ws + 98304);        // 32 KB
  int* validf      = (int*)(ws + 131072);       // 32 KB
  float* pers      = (float*)(ws + 163840);     // 8 KB
  float* cnts      = (float*)(ws + 172032);     // 8 KB
  uint32_t* semikey= (uint32_t*)(ws + 180224);  // 32 KB
  uint32_t* hardkey= (uint32_t*)(ws + 212992);  // 32 KB
  uint32_t* chnk   = (uint32_t*)(ws + 262144);  // 4 MB (total ~4.4 MB)
  float* out       = (float*)d_out;

  // jax.random.key(42) -> split
  uint32_t A0, B0, A1, B1;
  tf2x32(0u, 42u, 0u, 2u, A0, B0);
  tf2x32(0u, 42u, 1u, 3u, A1, B1);
  uint32_t kp0 = A0, kp1 = A1, kn0 = B0, kn1 = B1;

  pp_kernel<<<NPART, 256, 0, stream>>>(emb, labels, kp0, kp1, chnk, sq,
                                       posx, ap2lo, ap2hi, validf,
                                       semikey, hardkey);
  main_kernel<<<dim3(32, NCHUNK), 256, 0, stream>>>(chnk, labels, sq, ap2lo, ap2hi,
                                                    kn0, kn1, semikey, hardkey);
  finalize_kernel<<<NPART, 256, 0, stream>>>(emb, posx, validf, semikey, hardkey,
                                             pers, cnts);
  reduce_kernel<<<1, 256, 0, stream>>>(pers, cnts, out);
}